// Round 12
// baseline (818.843 us; speedup 1.0000x reference)
//
#include <hip/hip_runtime.h>
#include <cstdint>
#include <cstddef>

typedef _Float16 f16;
typedef _Float16 f16x8 __attribute__((ext_vector_type(8)));
typedef float    f32x4 __attribute__((ext_vector_type(4)));
typedef uint32_t u32x4 __attribute__((ext_vector_type(4)));

#define DEV static __device__ __forceinline__

constexpr int TOUT = 31;
constexpr int VOC  = 34004;
constexpr int VOCP = 34048;

// ---------------- ws layout (bytes) ----------------
constexpr size_t OFF_SYNC  = 0;                                         // 8192 (64 flags @128B)
constexpr size_t OFF_MEM16 = 8192;                                      // [3840][512] f16
constexpr size_t OFF_WMSWZ = OFF_MEM16 + (size_t)3840*512*2;            // [16][512][32] f16
constexpr size_t OFF_KEYS  = OFF_WMSWZ + (size_t)16*512*32*2;           // [3840][512] f16
constexpr size_t OFF_EMBA  = OFF_KEYS  + (size_t)3840*512*2;            // [1984][320] f16 (prep-only)
constexpr size_t OFF_WKTOP = OFF_EMBA  + (size_t)1984*320*2;            // [10][2048][32] f16 (prep-only)
constexpr size_t OFF_EMBW  = OFF_WKTOP + (size_t)10*2048*32*2;          // [1984][2048] f32 (perm cols)
constexpr size_t OFF_WA16  = OFF_EMBW  + (size_t)1984*2048*4;           // [1024][512] f16 rowmajor
constexpr size_t OFF_WKATT = OFF_WA16  + (size_t)1024*512*2;            // [16][2048][32] f16 (perm)
constexpr size_t OFF_WCA   = OFF_WKATT + (size_t)16*2048*32*2;          // [1024][2048] f32 (perm cols)
constexpr size_t OFF_WSTAR = OFF_WCA   + (size_t)1024*2048*4;           // [32][2048][32] f16 (perm)
constexpr size_t OFF_UK16  = OFF_WSTAR + (size_t)32*2048*32*2;          // [16][2048][32] f16 (perm)
constexpr size_t OFF_WQSWZ = OFF_UK16  + (size_t)16*2048*32*2;          // [16 r][512 n][32 kk] f16
constexpr size_t OFF_WASWZ = OFF_WQSWZ + (size_t)512*512*2;             // [32][512][32] f16
constexpr size_t OFF_H016  = OFF_WASWZ + (size_t)32*512*32*2;           // [64][512] f16
constexpr size_t OFF_YALL  = OFF_H016  + (size_t)64*512*2;              // [31][64][1024] f16
constexpr size_t OFF_ATT16 = OFF_YALL  + (size_t)31*64*1024*2;          // [1984][512] f16
constexpr size_t OFF_BKP   = OFF_ATT16 + (size_t)1984*512*2;            // [2048] f32 (perm bk)
constexpr size_t OFF_WFC   = OFF_BKP   + 8192;                          // [16][34048][32] f16
// q_part scratch aliases prep-only EMBA/WKTOP: [64 blk][16 b][512] f32 = 2 MB
constexpr size_t OFF_QP    = OFF_EMBA;

// ---------------- helpers ----------------
DEV void gload16(const void* src, void* ldsbase /* wave-uniform */) {
  __builtin_amdgcn_global_load_lds(
      (const __attribute__((address_space(1))) unsigned int*)src,
      (__attribute__((address_space(3))) unsigned int*)ldsbase, 16, 0, 0);
}

DEV float sigm(float x)      { return 1.f / (1.f + expf(-x)); }
DEV float tanh_fast(float x) { float e = __expf(2.f*x); return 1.f - 2.f/(e+1.f); }

DEV uint32_t aload_u32(const uint32_t* p){ return __hip_atomic_load(p, __ATOMIC_RELAXED, __HIP_MEMORY_SCOPE_AGENT); }
DEV void astore_u32(uint32_t* p, uint32_t v){ __hip_atomic_store(p, v, __ATOMIC_RELAXED, __HIP_MEMORY_SCOPE_AGENT); }

// wide agent-scope (sc1) transport
DEV void ld16_sc1(const void* p, u32x4& d){
  asm volatile("global_load_dwordx4 %0, %1, off sc1" : "=v"(d) : "v"(p));
}
DEV void st16_sc1(void* p, u32x4 v){
  asm volatile("global_store_dwordx4 %0, %1, off sc1" :: "v"(p), "v"(v) : "memory");
}
DEV void vwait(){ asm volatile("s_waitcnt vmcnt(0)" ::: "memory"); }

// ---------------- prep_all: elementwise conversions + swizzled B-layouts, one dispatch ----------------
__global__ void prep_all(char* ws, const int* dec, const float* h0, const float* memory,
                         const float* embt, const float* Wa, const float* bk,
                         const float* Wm, const float* Wk, const float* Uk, const float* Wq)
{
  const int blk = blockIdx.x, tid = threadIdx.x;

  if (blk < 464) {
    // ---- swizzle role (exact prep_swz body) ----
    int tg = blk*256 + tid;
    constexpr int S0=8192, S1=S0+20480, S2=S1+32768, S3=S2+32768, S4=S3+16384, S5=S4+8192;
    if (tg >= S5) return;
    f16 buf[32];
    f16* dst;
    if (tg < S0) {                       // Wm -> [16][512][32]
      int kt=tg>>9, n=tg&511;
      #pragma unroll
      for (int kk=0;kk<32;kk++) buf[kk] = (f16)Wm[(size_t)(kt*32+kk)*512 + n];
      dst = (f16*)(ws+OFF_WMSWZ) + (size_t)tg*32;
    } else if (tg < S1) {                // Wk rows 0..299 (pad->320), perm cols -> [10][2048][32]
      int j=tg-S0; int kt=j>>11, np=j&2047; int col=(np>>2)+(np&3)*512;
      #pragma unroll
      for (int kk=0;kk<32;kk++){ int k=kt*32+kk;
        buf[kk] = (k<300) ? (f16)Wk[(size_t)k*2048+col] : (f16)0.f; }
      dst = (f16*)(ws+OFF_WKTOP) + (size_t)j*32;
    } else if (tg < S2) {                // Wk rows 300..811, perm -> [16][2048][32]
      int j=tg-S1; int kt=j>>11, np=j&2047; int col=(np>>2)+(np&3)*512;
      #pragma unroll
      for (int kk=0;kk<32;kk++) buf[kk] = (f16)Wk[(size_t)(300+kt*32+kk)*2048+col];
      dst = (f16*)(ws+OFF_WKATT) + (size_t)j*32;
    } else if (tg < S3) {                // Uk, perm -> [16][2048][32]
      int j=tg-S2; int kt=j>>11, np=j&2047; int col=(np>>2)+(np&3)*512;
      #pragma unroll
      for (int kk=0;kk<32;kk++) buf[kk] = (f16)Uk[(size_t)(kt*32+kk)*2048+col];
      dst = (f16*)(ws+OFF_UK16) + (size_t)j*32;
    } else if (tg < S4) {                // Wa -> [32][512][32]
      int j=tg-S3; int kt=j>>9, n=j&511;
      #pragma unroll
      for (int kk=0;kk<32;kk++) buf[kk] = (f16)Wa[(size_t)(kt*32+kk)*512 + n];
      dst = (f16*)(ws+OFF_WASWZ) + (size_t)j*32;
    } else {                             // Wq -> [16 r][512 n][32 kk]
      int j=tg-S4; int rr=j>>9, n=j&511;
      #pragma unroll
      for (int kk=0;kk<32;kk++) buf[kk] = (f16)Wq[(size_t)(rr*32+kk)*512 + n];
      dst = (f16*)(ws+OFF_WQSWZ) + (size_t)j*32;
    }
    f16x8* d8 = (f16x8*)dst; f16x8* s8 = (f16x8*)buf;
    d8[0]=s8[0]; d8[1]=s8[1]; d8[2]=s8[2]; d8[3]=s8[3];
    return;
  }

  // ---- elementwise role (exact prep_elem body, 512-block grid-stride) ----
  f16* mem16 = (f16*)(ws+OFF_MEM16);
  f16* embA  = (f16*)(ws+OFF_EMBA);
  f16* wa16  = (f16*)(ws+OFF_WA16);
  f16* h016  = (f16*)(ws+OFF_H016);
  float* bkp = (float*)(ws+OFF_BKP);
  constexpr int E0=1966080, E1=E0+634880, E2=E1+524288, E3=E2+32768, E4=E3+2048;
  for (int i = (blk-464)*256 + tid; i < E4; i += 512*256) {
    if (i < E0) { mem16[i] = (f16)memory[i]; }
    else if (i < E1) { int j=i-E0; int r=j/320, k=j-r*320; int t=r>>6, b=r&63;
      int tok = dec[b*TOUT+t];
      embA[j] = (k<300) ? (f16)embt[(size_t)tok*300+k] : (f16)0.f; }
    else if (i < E2) { int j=i-E1; wa16[j] = (f16)Wa[j]; }
    else if (i < E3) { int j=i-E2; h016[j] = (f16)h0[j]; }
    else { int j=i-E3; bkp[j] = bk[(j>>2) + (j&3)*512]; }
  }
}

// ---------------- gemm3: keys | embW | Wca fused in one dispatch (<128,64,2,2> geometry) ----------------
__global__ __launch_bounds__(256, 1)
void gemm3(char* ws)
{
  constexpr int BM=128, BN=64, NT=256, AM=4, AN=2, NLA=2, NLB=1;
  __shared__ __align__(16) f16 sA[BM*32];
  __shared__ __align__(16) f16 sB[BN*32];

  const int blk = blockIdx.x, tid = threadIdx.x;
  const int wave = tid>>6, lane = tid&63;
  const int lg = lane>>4, lr = lane&15;

  const f16* A; int lda; const f16* Bs; int Np; void* C; const float* bias = nullptr;
  int bx, by, K, Mreal, mode;
  if (blk < 240) {           // keys = mem16 @ WMSWZ -> f16 [3840,512]
    bx = blk & 7; by = blk >> 3;
    A=(const f16*)(ws+OFF_MEM16); lda=512; Bs=(const f16*)(ws+OFF_WMSWZ); Np=512;
    C=ws+OFF_KEYS; K=512; Mreal=3840; mode=1;
  } else if (blk < 752) {    // embW = embA @ WKTOP + bkp -> f32 [1984,2048]
    int i=blk-240; bx=i&31; by=i>>5;
    A=(const f16*)(ws+OFF_EMBA); lda=320; Bs=(const f16*)(ws+OFF_WKTOP); Np=2048;
    C=ws+OFF_EMBW; bias=(const float*)(ws+OFF_BKP); K=320; Mreal=1984; mode=0;
  } else {                   // Wca = Wa16 @ WKATT -> f32 [1024,2048]
    int i=blk-752; bx=i&31; by=i>>5;
    A=(const f16*)(ws+OFF_WA16); lda=512; Bs=(const f16*)(ws+OFF_WKATT); Np=2048;
    C=ws+OFF_WCA; K=512; Mreal=1024; mode=0;
  }
  const int m0 = by*BM, n0 = bx*BN;
  const int wm = (wave>>1)*64, wn = (wave&1)*32;   // WR=2, WC=2

  f32x4 acc[AM][AN] = {};
  int aoff[AM], boff[AN];
  #pragma unroll
  for (int i=0;i<AM;i++){ int row = wm+i*16+lr; aoff[i] = row*64 + (((lg + (row>>1))&3)<<4); }
  #pragma unroll
  for (int i=0;i<AN;i++){ int row = wn+i*16+lr; boff[i] = row*64 + (((lg + (row>>1))&3)<<4); }

  const int ksteps = K/32;
  for (int ks=0; ks<ksteps; ks++){
    const int k0 = ks*32;
    __syncthreads();
    #pragma unroll
    for (int i=0;i<NLA;i++){
      int p = i*NT + tid;
      int row = p>>2; int g = ((p&3) - (row>>1)) & 3;
      int gm = m0+row; if (gm > Mreal-1) gm = Mreal-1;
      gload16(A + (size_t)gm*lda + k0 + g*8, (char*)sA + (i*NT + wave*64)*16);
    }
    #pragma unroll
    for (int i=0;i<NLB;i++){
      int p = i*NT + tid;
      int row = p>>2; int g = ((p&3) - (row>>1)) & 3;
      gload16(Bs + ((size_t)(k0>>5)*Np + (n0+row))*32 + g*8, (char*)sB + (i*NT + wave*64)*16);
    }
    __syncthreads();
    f16x8 af[AM], bf[AN];
    #pragma unroll
    for (int i=0;i<AM;i++) af[i] = *(const f16x8*)((const char*)sA + aoff[i]);
    #pragma unroll
    for (int i=0;i<AN;i++) bf[i] = *(const f16x8*)((const char*)sB + boff[i]);
    #pragma unroll
    for (int i=0;i<AM;i++)
      #pragma unroll
      for (int j=0;j<AN;j++)
        acc[i][j] = __builtin_amdgcn_mfma_f32_16x16x32_f16(af[i], bf[j], acc[i][j], 0,0,0);
  }

  #pragma unroll
  for (int i=0;i<AM;i++)
    #pragma unroll
    for (int j=0;j<AN;j++){
      int n = n0 + wn + j*16 + lr;
      float bb = (mode == 0 && bias) ? bias[n] : 0.f;
      #pragma unroll
      for (int r=0;r<4;r++){
        int m = m0 + wm + i*16 + lg*4 + r;
        if (m >= Mreal) continue;
        float v = acc[i][j][r] + bb;
        if (mode == 0) ((float*)C)[(size_t)m*Np + n] = v;
        else           ((f16*)C)[(size_t)m*Np + n] = (f16)v;
      }
    }
}

// ---------------- build W* = Wca + [Uk;0] -> [32][2048][32] (perm) ----------------
__global__ void build_wstar(char* ws, const float* Uk)
{
  int tg = blockIdx.x*256 + threadIdx.x;
  int kt = tg>>11, np = tg&2047;
  int col = (np>>2)+(np&3)*512;
  const float* wca = (const float*)(ws+OFF_WCA);
  f16 buf[32];
  #pragma unroll
  for (int kk=0;kk<32;kk++){
    int k = kt*32+kk;
    float v = wca[(size_t)k*2048 + np];
    if (k < 512) v += Uk[(size_t)k*2048 + col];
    buf[kk] = (f16)v;
  }
  f16* dst = (f16*)(ws+OFF_WSTAR) + (size_t)tg*32;
  f16x8* d8 = (f16x8*)dst; f16x8* s8 = (f16x8*)buf;
  d8[0]=s8[0]; d8[1]=s8[1]; d8[2]=s8[2]; d8[3]=s8[3];
}

// ---------------- generic fp16 MFMA GEMM (att + logits) ----------------
template<int BM, int BN, int WR, int WC, int MODE>
__global__ __launch_bounds__(WR*WC*64, 1)
void gemm16(const f16* __restrict__ A, int lda,
            const f16* __restrict__ Bs, int Np,
            void* __restrict__ C, const float* __restrict__ bias,
            int M, int K, int Mreal, int Nreal)
{
  constexpr int NT  = WR*WC*64;
  constexpr int WTM = BM/WR, WTN = BN/WC, AM = WTM/16, AN = WTN/16;
  constexpr int NLA = BM*64/(NT*16), NLB = BN*64/(NT*16);
  __shared__ __align__(16) f16 sA[BM*32];
  __shared__ __align__(16) f16 sB[BN*32];
  const int tid = threadIdx.x, wave = tid>>6, lane = tid&63;
  const int lg = lane>>4, lr = lane&15;
  const int m0 = blockIdx.y*BM, n0 = blockIdx.x*BN;
  const int wm = (wave/WC)*WTM, wn = (wave%WC)*WTN;

  f32x4 acc[AM][AN] = {};

  int aoff[AM], boff[AN];
  #pragma unroll
  for (int i=0;i<AM;i++){ int row = wm+i*16+lr; aoff[i] = row*64 + (((lg + (row>>1))&3)<<4); }
  #pragma unroll
  for (int i=0;i<AN;i++){ int row = wn+i*16+lr; boff[i] = row*64 + (((lg + (row>>1))&3)<<4); }

  const int ksteps = K/32;
  for (int ks=0; ks<ksteps; ks++){
    const int k0 = ks*32;
    __syncthreads();
    #pragma unroll
    for (int i=0;i<NLA;i++){
      int p = i*NT + tid;
      int row = p>>2; int g = ((p&3) - (row>>1)) & 3;
      int gm = m0+row; if (gm > Mreal-1) gm = Mreal-1;
      gload16(A + (size_t)gm*lda + k0 + g*8, (char*)sA + (i*NT + wave*64)*16);
    }
    #pragma unroll
    for (int i=0;i<NLB;i++){
      int p = i*NT + tid;
      int row = p>>2; int g = ((p&3) - (row>>1)) & 3;
      gload16(Bs + ((size_t)(k0>>5)*Np + (n0+row))*32 + g*8, (char*)sB + (i*NT + wave*64)*16);
    }
    __syncthreads();
    f16x8 af[AM], bf[AN];
    #pragma unroll
    for (int i=0;i<AM;i++) af[i] = *(const f16x8*)((const char*)sA + aoff[i]);
    #pragma unroll
    for (int i=0;i<AN;i++) bf[i] = *(const f16x8*)((const char*)sB + boff[i]);
    #pragma unroll
    for (int i=0;i<AM;i++)
      #pragma unroll
      for (int j=0;j<AN;j++)
        acc[i][j] = __builtin_amdgcn_mfma_f32_16x16x32_f16(af[i], bf[j], acc[i][j], 0,0,0);
  }

  #pragma unroll
  for (int i=0;i<AM;i++)
    #pragma unroll
    for (int j=0;j<AN;j++){
      int n = n0 + wn + j*16 + lr;
      if (MODE == 2 && n >= Nreal) continue;
      float bb = 0.f;
      if (MODE != 1 && bias) bb = bias[n];
      #pragma unroll
      for (int r=0;r<4;r++){
        int m = m0 + wm + i*16 + lg*4 + r;
        if (m >= Mreal) continue;
        float v = acc[i][j][r] + bb;
        if (MODE == 0)      ((float*)C)[(size_t)m*Np + n] = v;
        else if (MODE == 1) ((f16*)C)[(size_t)m*Np + n] = (f16)v;
        else { int t = m>>6, b = m&63; ((float*)C)[((size_t)(b*TOUT+t))*VOC + n] = v; }
      }
    }
}

// ---------------- cluster barrier: sc1 flag array (proven) ----------------
DEV void cbar(uint32_t* flags, int cbase, int r, int tid, uint32_t target)
{
  vwait();
  __syncthreads();
  if (tid == 0)
    astore_u32(flags + (size_t)(cbase + r)*32, target);
  if (tid < 16) {
    while (aload_u32(flags + (size_t)(cbase + tid)*32) < target)
      __builtin_amdgcn_s_sleep(1);
  }
  __syncthreads();
}

// ---------------- P1 inner: one 16x16 tile over K, 8-deep B prefetch ----------------
template<int KS>
DEV f32x4 p1_mfma(const f16* __restrict__ Bs, const char* ylb, int col, int kg, int lr)
{
  f16x8 B[8];
  #pragma unroll
  for (int i=0;i<8;i++)
    B[i] = *(const f16x8*)(Bs + (((size_t)i*2048 + col)<<5) + kg*8);
  f32x4 acc = {};
  #pragma unroll
  for (int ks=0; ks<KS; ks+=8) {
    #pragma unroll
    for (int i=0;i<8;i++) {
      f16x8 a = *(const f16x8*)(ylb + lr*2064 + (ks+i)*64 + kg*16);
      acc = __builtin_amdgcn_mfma_f32_16x16x32_f16(a, B[i], acc, 0,0,0);
      int nk = ks+8+i;
      if (nk < KS)
        B[i] = *(const f16x8*)(Bs + (((size_t)nk*2048 + col)<<5) + kg*8);
    }
  }
  return acc;
}

// ---------------- recur (blocks 0-63) + independent Wfc converters (64-203) ----------------
__global__ __launch_bounds__(512, 1)
void recur_wfc(char* ws, const float* __restrict__ c0, const float* __restrict__ v_att,
               const float* __restrict__ Wfc)
{
  const int blk = blockIdx.x, tid = threadIdx.x;

  if (blk >= 64) {
    // -------- Wfc f32 -> swizzled f16 [16][VOCP][32]; no sync, no LDS, no flags --------
    const int cb = blk - 64;                      // 0..139
    const int n = cb*256 + (tid & 255);
    const int kt0 = (tid >> 8) * 8;
    if (n < VOCP) {
      f16* wdst = (f16*)(ws+OFF_WFC);
      for (int kt = kt0; kt < kt0+8; kt++) {
        f16 buf[32];
        #pragma unroll
        for (int kk=0;kk<32;kk++)
          buf[kk] = (n < VOC) ? (f16)Wfc[(size_t)(kt*32+kk)*VOC + n] : (f16)0.f;
        f16x8* d8 = (f16x8*)((f16*)wdst + ((size_t)kt*VOCP + n)*32);
        f16x8* s8 = (f16x8*)buf;
        d8[0]=s8[0]; d8[1]=s8[1]; d8[2]=s8[2]; d8[3]=s8[3];
      }
    }
    return;
  }

  // -------------------- recur role (R7, proven) --------------------
  const int wave = tid>>6, lane = tid&63;
  const int lr = lane&15, kg = lane>>4;
  const int clus = blk>>4, r = blk&15;
  const int cbase = clus<<4;
  const int bown = cbase + r;
  const int n0 = r*128;

  uint32_t* flags = (uint32_t*)(ws+OFF_SYNC);
  char* qpg = (char*)(ws+OFF_QP);
  const f16* wstar = (const f16*)(ws+OFF_WSTAR);
  const f16* uk16  = (const f16*)(ws+OFF_UK16);
  const f16* wqswz = (const f16*)(ws+OFF_WQSWZ);
  const f16* keys16= (const f16*)(ws+OFF_KEYS);
  const f16* mem16 = (const f16*)(ws+OFF_MEM16);
  const float* embw= (const float*)(ws+OFF_EMBW);

  __shared__ __align__(16) char  ybuf[33024];
  __shared__ __align__(16) float zl[16*132];
  __shared__ __align__(16) float c_sl[512];
  __shared__ __align__(16) f16   h_sl[512];
  __shared__ __align__(16) float q_l[512];
  __shared__ __align__(16) float v_l[512];
  __shared__ __align__(16) f16   cx16_l[512];
  __shared__ __align__(16) float sc_l[64];
  __shared__ __align__(16) f16   mem_lds[60*512];

  v_l[tid] = v_att[tid];
  { int b = tid>>5, uu = tid&31;
    c_sl[tid] = c0[(size_t)(cbase+b)*512 + r*32 + uu]; }

  {
    const char* msrc = (const char*)(mem16 + (size_t)bown*60*512);
    #pragma unroll
    for (int i=0;i<8;i++){
      int cb2 = i*512 + wave*64;
      if (cb2 < 3840)
        gload16(msrc + ((size_t)cb2 + lane)*16, (char*)mem_lds + (size_t)cb2*16);
    }
  }

  for (int t=0; t<TOUT; t++){
    // A: gather y(t-1) (wide sc1)
    {
      const char* ysrc; int rsh;
      if (t == 0) { ysrc = ws+OFF_H016; rsh = 6; }
      else        { ysrc = ws+OFF_YALL + (size_t)(t-1)*64*2048; rsh = 7; }
      const int npass = (16 << rsh) >> 9;
      u32x4 g[4];
      #pragma unroll
      for (int p=0;p<4;p++){
        if (p < npass){
          int cid = p*512 + tid, row = cid>>rsh, off = cid & ((1<<rsh)-1);
          ld16_sc1(ysrc + ((size_t)(cbase+row) << (rsh+4)) + off*16, g[p]);
        }
      }
      vwait();
      #pragma unroll
      for (int p=0;p<4;p++){
        if (p < npass){
          int cid = p*512 + tid, row = cid>>rsh, off = cid & ((1<<rsh)-1);
          *(u32x4*)(ybuf + row*2064 + off*16) = g[p];
        }
      }
      __syncthreads();
    }

    // B: P1 z[16 b][own 128 cols] via MFMA -> LDS
    {
      const int col = n0 + wave*16 + lr;
      f32x4 acc = (t==0) ? p1_mfma<16>(uk16,  ybuf, col, kg, lr)
                         : p1_mfma<32>(wstar, ybuf, col, kg, lr);
      #pragma unroll
      for (int rr=0;rr<4;rr++)
        zl[(kg*4+rr)*132 + wave*16 + lr] = acc[rr];
    }
    __syncthreads();

    // gates + c/h update
    {
      const int b = tid>>5, uu = tid&31;
      f32x4 zz = *(const f32x4*)(zl + b*132 + uu*4);
      f32x4 e  = *(const f32x4*)(embw + ((size_t)(t*64+cbase+b))*2048 + n0 + uu*4);
      float ig = sigm(zz[0]+e[0]), fg = sigm(zz[1]+e[1]);
      float gg = tanhf(zz[2]+e[2]), og = sigm(zz[3]+e[3]);
      float cn = fg*c_sl[tid] + ig*gg;
      c_sl[tid] = cn;
      h_sl[tid] = (f16)(og * tanhf(cn));
    }
    __syncthreads();

    // C: publish h slices
    char* yt = (char*)(ws+OFF_YALL) + (size_t)t*64*2048;
    if (tid < 64){
      int b = tid>>2, off = tid&3;
      u32x4 v = *(const u32x4*)((const char*)h_sl + b*64 + off*16);
      st16_sc1(yt + (size_t)(cbase+b)*2048 + r*64 + off*16, v);
    }

    // D: q_part = h_slice @ Wq_slice -> LDS stage, publish wide
    {
      float* qs = (float*)ybuf;
      f16x8 a = *(const f16x8*)(h_sl + lr*32 + kg*8);
      #pragma unroll
      for (int j=0;j<4;j++){
        int n = wave*64 + j*16 + lr;
        f16x8 bf = *(const f16x8*)(wqswz + ((size_t)(r*512 + n))*32 + kg*8);
        f32x4 aq = __builtin_amdgcn_mfma_f32_16x16x32_f16(a, bf, (f32x4){0.f,0.f,0.f,0.f}, 0,0,0);
        #pragma unroll
        for (int rr=0;rr<4;rr++)
          qs[(kg*4+rr)*512 + n] = aq[rr];
      }
    }
    __syncthreads();
    {
      #pragma unroll
      for (int p=0;p<4;p++){
        int cid = p*512 + tid;
        u32x4 v = *(const u32x4*)(ybuf + cid*16);
        st16_sc1(qpg + (size_t)blk*32768 + cid*16, v);
      }
    }
    cbar(flags, cbase, r, tid, 2*t+1);

    // F: gather own batch's 16 q-partials, sum
    {
      u32x4 gq[4];
      #pragma unroll
      for (int p=0;p<4;p++){
        int cid = p*512 + tid, s = cid>>7, off = cid&127;
        ld16_sc1(qpg + (size_t)(cbase+s)*32768 + r*2048 + off*16, gq[p]);
      }
      vwait();
      #pragma unroll
      for (int p=0;p<4;p++){
        int cid = p*512 + tid;
        *(u32x4*)(ybuf + cid*16) = gq[p];
      }
      __syncthreads();
      const float* qin = (const float*)ybuf;
      float qsum = 0.f;
      #pragma unroll
      for (int s=0;s<16;s++) qsum += qin[s*512 + tid];
      q_l[tid] = qsum;
    }
    __syncthreads();

    // G: scores -> softmax -> ctx
    for (int i = wave; i < 60; i += 8){
      const f16* krow = keys16 + ((size_t)(bown*60+i))*512;
      float p = 0.f;
      #pragma unroll
      for (int s=0;s<8;s++){
        int u = lane + s*64;
        p += tanh_fast((float)krow[u] + q_l[u]) * v_l[u];
      }
      #pragma unroll
      for (int m=32;m;m>>=1) p += __shfl_xor(p, m, 64);
      if (lane == 0) sc_l[i] = p;
    }
    __syncthreads();
    if (wave == 0){
      float s = (lane < 60) ? sc_l[lane] : -1e30f;
      float mx = s;
      #pragma unroll
      for (int m=32;m;m>>=1) mx = fmaxf(mx, __shfl_xor(mx, m, 64));
      float ev = (lane < 60) ? __expf(s - mx) : 0.f;
      float sum = ev;
      #pragma unroll
      for (int m=32;m;m>>=1) sum += __shfl_xor(sum, m, 64);
      if (lane < 60) sc_l[lane] = ev / sum;
    }
    __syncthreads();
    {
      float cx = 0.f;
      #pragma unroll
      for (int i=0;i<60;i++) cx += sc_l[i] * (float)mem_lds[i*512 + tid];
      cx16_l[tid] = (f16)cx;
    }
    __syncthreads();
    if (tid < 64){
      u32x4 v = *(const u32x4*)((const char*)cx16_l + tid*16);
      st16_sc1(yt + (size_t)bown*2048 + 1024 + tid*16, v);
    }
    cbar(flags, cbase, r, tid, 2*t+2);
  }
}

// ---------------- host ----------------
extern "C" void kernel_launch(void* const* d_in, const int* in_sizes, int n_in,
                              void* d_out, int out_size, void* d_ws, size_t ws_size,
                              hipStream_t stream)
{
  const int*   dec  = (const int*)  d_in[0];
  const float* h0   = (const float*)d_in[1];
  const float* c0   = (const float*)d_in[2];
  const float* mem  = (const float*)d_in[3];
  const float* embt = (const float*)d_in[4];
  const float* Wk   = (const float*)d_in[5];
  const float* Uk   = (const float*)d_in[6];
  const float* bk   = (const float*)d_in[7];
  const float* Wm   = (const float*)d_in[8];
  const float* Wq   = (const float*)d_in[9];
  const float* va   = (const float*)d_in[10];
  const float* Wa   = (const float*)d_in[11];
  const float* Wfc  = (const float*)d_in[12];
  const float* bfc  = (const float*)d_in[13];
  char* ws = (char*)d_ws;

  hipMemsetAsync(ws + OFF_SYNC, 0, 8192, stream);

  // prep (elementwise + swizzles) in one dispatch
  prep_all<<<976, 256, 0, stream>>>(ws, dec, h0, mem, embt, Wa, bk, Wm, Wk, Uk, Wq);

  // keys | embW | Wca fused in one dispatch
  gemm3<<<1008, 256, 0, stream>>>(ws);

  build_wstar<<<256, 256, 0, stream>>>(ws, Uk);

  // recurrence (blocks 0-63) + Wfc conversion hidden in the same dispatch (64-203)
  recur_wfc<<<204, 512, 0, stream>>>(ws, c0, va, Wfc);

  // attn_all = Y @ Wa : [1984,512] f16
  gemm16<128,64,2,2,1><<<dim3(8,16), 256, 0, stream>>>(
      (const f16*)(ws+OFF_YALL), 1024, (const f16*)(ws+OFF_WASWZ), 512,
      ws+OFF_ATT16, nullptr, 1984, 1024, 1984, 512);

  // logits = attn_all @ Wfc + bfc -> d_out [b][t][vocab]  (BM=512: 4 m-passes, denser MFMA)
  gemm16<512,128,4,2,2><<<dim3(266,4), 512, 0, stream>>>(
      (const f16*)(ws+OFF_ATT16), 512, (const f16*)(ws+OFF_WFC), VOCP,
      d_out, bfc, 1984, 512, 1984, VOC);
}

// Round 13
// 766.447 us; speedup vs baseline: 1.0684x; 1.0684x over previous
//
#include <hip/hip_runtime.h>
#include <cstdint>
#include <cstddef>

typedef _Float16 f16;
typedef _Float16 f16x8 __attribute__((ext_vector_type(8)));
typedef float    f32x4 __attribute__((ext_vector_type(4)));
typedef uint32_t u32x4 __attribute__((ext_vector_type(4)));

#define DEV static __device__ __forceinline__

constexpr int TOUT = 31;
constexpr int VOC  = 34004;
constexpr int VOCP = 34048;

// ---------------- ws layout (bytes) ----------------
constexpr size_t OFF_SYNC  = 0;                                         // 8192 (64 flags @128B)
constexpr size_t OFF_MEM16 = 8192;                                      // [3840][512] f16
constexpr size_t OFF_WMSWZ = OFF_MEM16 + (size_t)3840*512*2;            // [16][512][32] f16
constexpr size_t OFF_KEYS  = OFF_WMSWZ + (size_t)16*512*32*2;           // [3840][512] f16
constexpr size_t OFF_EMBA  = OFF_KEYS  + (size_t)3840*512*2;            // [1984][320] f16 (prep-only)
constexpr size_t OFF_WKTOP = OFF_EMBA  + (size_t)1984*320*2;            // [10][2048][32] f16 (prep-only)
constexpr size_t OFF_EMBW  = OFF_WKTOP + (size_t)10*2048*32*2;          // [1984][2048] f32 (perm cols)
constexpr size_t OFF_WA16  = OFF_EMBW  + (size_t)1984*2048*4;           // [1024][512] f16 rowmajor
constexpr size_t OFF_WKATT = OFF_WA16  + (size_t)1024*512*2;            // [16][2048][32] f16 (perm)
constexpr size_t OFF_WCA   = OFF_WKATT + (size_t)16*2048*32*2;          // [1024][2048] f32 (perm cols)
constexpr size_t OFF_WSTAR = OFF_WCA   + (size_t)1024*2048*4;           // [32][2048][32] f16 (perm)
constexpr size_t OFF_UK16  = OFF_WSTAR + (size_t)32*2048*32*2;          // [16][2048][32] f16 (perm)
constexpr size_t OFF_WQSWZ = OFF_UK16  + (size_t)16*2048*32*2;          // [16 r][512 n][32 kk] f16
constexpr size_t OFF_WASWZ = OFF_WQSWZ + (size_t)512*512*2;             // [32][512][32] f16
constexpr size_t OFF_H016  = OFF_WASWZ + (size_t)32*512*32*2;           // [64][512] f16
constexpr size_t OFF_YALL  = OFF_H016  + (size_t)64*512*2;              // [31][64][1024] f16
constexpr size_t OFF_ATT16 = OFF_YALL  + (size_t)31*64*1024*2;          // [1984][512] f16
constexpr size_t OFF_BKP   = OFF_ATT16 + (size_t)1984*512*2;            // [2048] f32 (perm bk)
constexpr size_t OFF_WFC   = OFF_BKP   + 8192;                          // [16][34048][32] f16
// q_part scratch aliases prep-only EMBA/WKTOP: [64 blk][16 b][512] f32 = 2 MB
constexpr size_t OFF_QP    = OFF_EMBA;

// ---------------- helpers ----------------
DEV void gload16(const void* src, void* ldsbase /* wave-uniform */) {
  __builtin_amdgcn_global_load_lds(
      (const __attribute__((address_space(1))) unsigned int*)src,
      (__attribute__((address_space(3))) unsigned int*)ldsbase, 16, 0, 0);
}

DEV float sigm(float x)      { return 1.f / (1.f + expf(-x)); }
DEV float tanh_fast(float x) { float e = __expf(2.f*x); return 1.f - 2.f/(e+1.f); }

DEV uint32_t aload_u32(const uint32_t* p){ return __hip_atomic_load(p, __ATOMIC_RELAXED, __HIP_MEMORY_SCOPE_AGENT); }
DEV void astore_u32(uint32_t* p, uint32_t v){ __hip_atomic_store(p, v, __ATOMIC_RELAXED, __HIP_MEMORY_SCOPE_AGENT); }

// wide agent-scope (sc1) transport
DEV void ld16_sc1(const void* p, u32x4& d){
  asm volatile("global_load_dwordx4 %0, %1, off sc1" : "=v"(d) : "v"(p));
}
DEV void st16_sc1(void* p, u32x4 v){
  asm volatile("global_store_dwordx4 %0, %1, off sc1" :: "v"(p), "v"(v) : "memory");
}
DEV void vwait(){ asm volatile("s_waitcnt vmcnt(0)" ::: "memory"); }

// ---------------- prep_all: elementwise conversions + swizzled B-layouts, one dispatch ----------------
__global__ void prep_all(char* ws, const int* dec, const float* h0, const float* memory,
                         const float* embt, const float* Wa, const float* bk,
                         const float* Wm, const float* Wk, const float* Uk, const float* Wq)
{
  const int blk = blockIdx.x, tid = threadIdx.x;

  if (blk < 464) {
    // ---- swizzle role ----
    int tg = blk*256 + tid;
    constexpr int S0=8192, S1=S0+20480, S2=S1+32768, S3=S2+32768, S4=S3+16384, S5=S4+8192;
    if (tg >= S5) return;
    f16 buf[32];
    f16* dst;
    if (tg < S0) {                       // Wm -> [16][512][32]
      int kt=tg>>9, n=tg&511;
      #pragma unroll
      for (int kk=0;kk<32;kk++) buf[kk] = (f16)Wm[(size_t)(kt*32+kk)*512 + n];
      dst = (f16*)(ws+OFF_WMSWZ) + (size_t)tg*32;
    } else if (tg < S1) {                // Wk rows 0..299 (pad->320), perm cols -> [10][2048][32]
      int j=tg-S0; int kt=j>>11, np=j&2047; int col=(np>>2)+(np&3)*512;
      #pragma unroll
      for (int kk=0;kk<32;kk++){ int k=kt*32+kk;
        buf[kk] = (k<300) ? (f16)Wk[(size_t)k*2048+col] : (f16)0.f; }
      dst = (f16*)(ws+OFF_WKTOP) + (size_t)j*32;
    } else if (tg < S2) {                // Wk rows 300..811, perm -> [16][2048][32]
      int j=tg-S1; int kt=j>>11, np=j&2047; int col=(np>>2)+(np&3)*512;
      #pragma unroll
      for (int kk=0;kk<32;kk++) buf[kk] = (f16)Wk[(size_t)(300+kt*32+kk)*2048+col];
      dst = (f16*)(ws+OFF_WKATT) + (size_t)j*32;
    } else if (tg < S3) {                // Uk, perm -> [16][2048][32]
      int j=tg-S2; int kt=j>>11, np=j&2047; int col=(np>>2)+(np&3)*512;
      #pragma unroll
      for (int kk=0;kk<32;kk++) buf[kk] = (f16)Uk[(size_t)(kt*32+kk)*2048+col];
      dst = (f16*)(ws+OFF_UK16) + (size_t)j*32;
    } else if (tg < S4) {                // Wa -> [32][512][32]
      int j=tg-S3; int kt=j>>9, n=j&511;
      #pragma unroll
      for (int kk=0;kk<32;kk++) buf[kk] = (f16)Wa[(size_t)(kt*32+kk)*512 + n];
      dst = (f16*)(ws+OFF_WASWZ) + (size_t)j*32;
    } else {                             // Wq -> [16 r][512 n][32 kk]
      int j=tg-S4; int rr=j>>9, n=j&511;
      #pragma unroll
      for (int kk=0;kk<32;kk++) buf[kk] = (f16)Wq[(size_t)(rr*32+kk)*512 + n];
      dst = (f16*)(ws+OFF_WQSWZ) + (size_t)j*32;
    }
    f16x8* d8 = (f16x8*)dst; f16x8* s8 = (f16x8*)buf;
    d8[0]=s8[0]; d8[1]=s8[1]; d8[2]=s8[2]; d8[3]=s8[3];
    return;
  }

  // ---- elementwise role ----
  f16* mem16 = (f16*)(ws+OFF_MEM16);
  f16* embA  = (f16*)(ws+OFF_EMBA);
  f16* wa16  = (f16*)(ws+OFF_WA16);
  f16* h016  = (f16*)(ws+OFF_H016);
  float* bkp = (float*)(ws+OFF_BKP);
  constexpr int E0=1966080, E1=E0+634880, E2=E1+524288, E3=E2+32768, E4=E3+2048;
  for (int i = (blk-464)*256 + tid; i < E4; i += 512*256) {
    if (i < E0) { mem16[i] = (f16)memory[i]; }
    else if (i < E1) { int j=i-E0; int r=j/320, k=j-r*320; int t=r>>6, b=r&63;
      int tok = dec[b*TOUT+t];
      embA[j] = (k<300) ? (f16)embt[(size_t)tok*300+k] : (f16)0.f; }
    else if (i < E2) { int j=i-E1; wa16[j] = (f16)Wa[j]; }
    else if (i < E3) { int j=i-E2; h016[j] = (f16)h0[j]; }
    else { int j=i-E3; bkp[j] = bk[(j>>2) + (j&3)*512]; }
  }
}

// ---------------- gemm3: keys | embW | Wca fused in one dispatch (<128,64,2,2> geometry) ----------------
__global__ __launch_bounds__(256, 1)
void gemm3(char* ws)
{
  constexpr int BM=128, BN=64, NT=256, AM=4, AN=2, NLA=2, NLB=1;
  __shared__ __align__(16) f16 sA[BM*32];
  __shared__ __align__(16) f16 sB[BN*32];

  const int blk = blockIdx.x, tid = threadIdx.x;
  const int wave = tid>>6, lane = tid&63;
  const int lg = lane>>4, lr = lane&15;

  const f16* A; int lda; const f16* Bs; int Np; void* C; const float* bias = nullptr;
  int bx, by, K, Mreal, mode;
  if (blk < 240) {           // keys = mem16 @ WMSWZ -> f16 [3840,512]
    bx = blk & 7; by = blk >> 3;
    A=(const f16*)(ws+OFF_MEM16); lda=512; Bs=(const f16*)(ws+OFF_WMSWZ); Np=512;
    C=ws+OFF_KEYS; K=512; Mreal=3840; mode=1;
  } else if (blk < 752) {    // embW = embA @ WKTOP + bkp -> f32 [1984,2048]
    int i=blk-240; bx=i&31; by=i>>5;
    A=(const f16*)(ws+OFF_EMBA); lda=320; Bs=(const f16*)(ws+OFF_WKTOP); Np=2048;
    C=ws+OFF_EMBW; bias=(const float*)(ws+OFF_BKP); K=320; Mreal=1984; mode=0;
  } else {                   // Wca = Wa16 @ WKATT -> f32 [1024,2048]
    int i=blk-752; bx=i&31; by=i>>5;
    A=(const f16*)(ws+OFF_WA16); lda=512; Bs=(const f16*)(ws+OFF_WKATT); Np=2048;
    C=ws+OFF_WCA; K=512; Mreal=1024; mode=0;
  }
  const int m0 = by*BM, n0 = bx*BN;
  const int wm = (wave>>1)*64, wn = (wave&1)*32;   // WR=2, WC=2

  f32x4 acc[AM][AN] = {};
  int aoff[AM], boff[AN];
  #pragma unroll
  for (int i=0;i<AM;i++){ int row = wm+i*16+lr; aoff[i] = row*64 + (((lg + (row>>1))&3)<<4); }
  #pragma unroll
  for (int i=0;i<AN;i++){ int row = wn+i*16+lr; boff[i] = row*64 + (((lg + (row>>1))&3)<<4); }

  const int ksteps = K/32;
  for (int ks=0; ks<ksteps; ks++){
    const int k0 = ks*32;
    __syncthreads();
    #pragma unroll
    for (int i=0;i<NLA;i++){
      int p = i*NT + tid;
      int row = p>>2; int g = ((p&3) - (row>>1)) & 3;
      int gm = m0+row; if (gm > Mreal-1) gm = Mreal-1;
      gload16(A + (size_t)gm*lda + k0 + g*8, (char*)sA + (i*NT + wave*64)*16);
    }
    #pragma unroll
    for (int i=0;i<NLB;i++){
      int p = i*NT + tid;
      int row = p>>2; int g = ((p&3) - (row>>1)) & 3;
      gload16(Bs + ((size_t)(k0>>5)*Np + (n0+row))*32 + g*8, (char*)sB + (i*NT + wave*64)*16);
    }
    __syncthreads();
    f16x8 af[AM], bf[AN];
    #pragma unroll
    for (int i=0;i<AM;i++) af[i] = *(const f16x8*)((const char*)sA + aoff[i]);
    #pragma unroll
    for (int i=0;i<AN;i++) bf[i] = *(const f16x8*)((const char*)sB + boff[i]);
    #pragma unroll
    for (int i=0;i<AM;i++)
      #pragma unroll
      for (int j=0;j<AN;j++)
        acc[i][j] = __builtin_amdgcn_mfma_f32_16x16x32_f16(af[i], bf[j], acc[i][j], 0,0,0);
  }

  #pragma unroll
  for (int i=0;i<AM;i++)
    #pragma unroll
    for (int j=0;j<AN;j++){
      int n = n0 + wn + j*16 + lr;
      float bb = (mode == 0 && bias) ? bias[n] : 0.f;
      #pragma unroll
      for (int r=0;r<4;r++){
        int m = m0 + wm + i*16 + lg*4 + r;
        if (m >= Mreal) continue;
        float v = acc[i][j][r] + bb;
        if (mode == 0) ((float*)C)[(size_t)m*Np + n] = v;
        else           ((f16*)C)[(size_t)m*Np + n] = (f16)v;
      }
    }
}

// ---------------- build W* = Wca + [Uk;0] -> [32][2048][32] (perm) ----------------
__global__ void build_wstar(char* ws, const float* Uk)
{
  int tg = blockIdx.x*256 + threadIdx.x;
  int kt = tg>>11, np = tg&2047;
  int col = (np>>2)+(np&3)*512;
  const float* wca = (const float*)(ws+OFF_WCA);
  f16 buf[32];
  #pragma unroll
  for (int kk=0;kk<32;kk++){
    int k = kt*32+kk;
    float v = wca[(size_t)k*2048 + np];
    if (k < 512) v += Uk[(size_t)k*2048 + col];
    buf[kk] = (f16)v;
  }
  f16* dst = (f16*)(ws+OFF_WSTAR) + (size_t)tg*32;
  f16x8* d8 = (f16x8*)dst; f16x8* s8 = (f16x8*)buf;
  d8[0]=s8[0]; d8[1]=s8[1]; d8[2]=s8[2]; d8[3]=s8[3];
}

// ---------------- generic fp16 MFMA GEMM (att + logits) ----------------
template<int BM, int BN, int WR, int WC, int MODE>
__global__ __launch_bounds__(WR*WC*64, 1)
void gemm16(const f16* __restrict__ A, int lda,
            const f16* __restrict__ Bs, int Np,
            void* __restrict__ C, const float* __restrict__ bias,
            int M, int K, int Mreal, int Nreal)
{
  constexpr int NT  = WR*WC*64;
  constexpr int WTM = BM/WR, WTN = BN/WC, AM = WTM/16, AN = WTN/16;
  constexpr int NLA = BM*64/(NT*16), NLB = BN*64/(NT*16);
  __shared__ __align__(16) f16 sA[BM*32];
  __shared__ __align__(16) f16 sB[BN*32];
  const int tid = threadIdx.x, wave = tid>>6, lane = tid&63;
  const int lg = lane>>4, lr = lane&15;
  const int m0 = blockIdx.y*BM, n0 = blockIdx.x*BN;
  const int wm = (wave/WC)*WTM, wn = (wave%WC)*WTN;

  f32x4 acc[AM][AN] = {};

  int aoff[AM], boff[AN];
  #pragma unroll
  for (int i=0;i<AM;i++){ int row = wm+i*16+lr; aoff[i] = row*64 + (((lg + (row>>1))&3)<<4); }
  #pragma unroll
  for (int i=0;i<AN;i++){ int row = wn+i*16+lr; boff[i] = row*64 + (((lg + (row>>1))&3)<<4); }

  const int ksteps = K/32;
  for (int ks=0; ks<ksteps; ks++){
    const int k0 = ks*32;
    __syncthreads();
    #pragma unroll
    for (int i=0;i<NLA;i++){
      int p = i*NT + tid;
      int row = p>>2; int g = ((p&3) - (row>>1)) & 3;
      int gm = m0+row; if (gm > Mreal-1) gm = Mreal-1;
      gload16(A + (size_t)gm*lda + k0 + g*8, (char*)sA + (i*NT + wave*64)*16);
    }
    #pragma unroll
    for (int i=0;i<NLB;i++){
      int p = i*NT + tid;
      int row = p>>2; int g = ((p&3) - (row>>1)) & 3;
      gload16(Bs + ((size_t)(k0>>5)*Np + (n0+row))*32 + g*8, (char*)sB + (i*NT + wave*64)*16);
    }
    __syncthreads();
    f16x8 af[AM], bf[AN];
    #pragma unroll
    for (int i=0;i<AM;i++) af[i] = *(const f16x8*)((const char*)sA + aoff[i]);
    #pragma unroll
    for (int i=0;i<AN;i++) bf[i] = *(const f16x8*)((const char*)sB + boff[i]);
    #pragma unroll
    for (int i=0;i<AM;i++)
      #pragma unroll
      for (int j=0;j<AN;j++)
        acc[i][j] = __builtin_amdgcn_mfma_f32_16x16x32_f16(af[i], bf[j], acc[i][j], 0,0,0);
  }

  #pragma unroll
  for (int i=0;i<AM;i++)
    #pragma unroll
    for (int j=0;j<AN;j++){
      int n = n0 + wn + j*16 + lr;
      if (MODE == 2 && n >= Nreal) continue;
      float bb = 0.f;
      if (MODE != 1 && bias) bb = bias[n];
      #pragma unroll
      for (int r=0;r<4;r++){
        int m = m0 + wm + i*16 + lg*4 + r;
        if (m >= Mreal) continue;
        float v = acc[i][j][r] + bb;
        if (MODE == 0)      ((float*)C)[(size_t)m*Np + n] = v;
        else if (MODE == 1) ((f16*)C)[(size_t)m*Np + n] = (f16)v;
        else { int t = m>>6, b = m&63; ((float*)C)[((size_t)(b*TOUT+t))*VOC + n] = v; }
      }
    }
}

// ---------------- cluster barrier: sc1 flag array (proven) ----------------
DEV void cbar(uint32_t* flags, int cbase, int r, int tid, uint32_t target)
{
  vwait();
  __syncthreads();
  if (tid == 0)
    astore_u32(flags + (size_t)(cbase + r)*32, target);
  if (tid < 16) {
    while (aload_u32(flags + (size_t)(cbase + tid)*32) < target)
      __builtin_amdgcn_s_sleep(1);
  }
  __syncthreads();
}

// ---------------- P1 inner: one 16x16 tile over K, 8-deep B prefetch ----------------
template<int KS>
DEV f32x4 p1_mfma(const f16* __restrict__ Bs, const char* ylb, int col, int kg, int lr)
{
  f16x8 B[8];
  #pragma unroll
  for (int i=0;i<8;i++)
    B[i] = *(const f16x8*)(Bs + (((size_t)i*2048 + col)<<5) + kg*8);
  f32x4 acc = {};
  #pragma unroll
  for (int ks=0; ks<KS; ks+=8) {
    #pragma unroll
    for (int i=0;i<8;i++) {
      f16x8 a = *(const f16x8*)(ylb + lr*2064 + (ks+i)*64 + kg*16);
      acc = __builtin_amdgcn_mfma_f32_16x16x32_f16(a, B[i], acc, 0,0,0);
      int nk = ks+8+i;
      if (nk < KS)
        B[i] = *(const f16x8*)(Bs + (((size_t)nk*2048 + col)<<5) + kg*8);
    }
  }
  return acc;
}

// ---------------- recur (blocks 0-63) + independent Wfc converters (64-203) ----------------
__global__ __launch_bounds__(512, 1)
void recur_wfc(char* ws, const float* __restrict__ c0, const float* __restrict__ v_att,
               const float* __restrict__ Wfc)
{
  const int blk = blockIdx.x, tid = threadIdx.x;

  if (blk >= 64) {
    // -------- Wfc f32 -> swizzled f16 [16][VOCP][32]; no sync, no LDS, no flags --------
    const int cb = blk - 64;                      // 0..139
    const int n = cb*256 + (tid & 255);
    const int kt0 = (tid >> 8) * 8;
    if (n < VOCP) {
      f16* wdst = (f16*)(ws+OFF_WFC);
      for (int kt = kt0; kt < kt0+8; kt++) {
        f16 buf[32];
        #pragma unroll
        for (int kk=0;kk<32;kk++)
          buf[kk] = (n < VOC) ? (f16)Wfc[(size_t)(kt*32+kk)*VOC + n] : (f16)0.f;
        f16x8* d8 = (f16x8*)((f16*)wdst + ((size_t)kt*VOCP + n)*32);
        f16x8* s8 = (f16x8*)buf;
        d8[0]=s8[0]; d8[1]=s8[1]; d8[2]=s8[2]; d8[3]=s8[3];
      }
    }
    return;
  }

  // -------------------- recur role (R7, proven) --------------------
  const int wave = tid>>6, lane = tid&63;
  const int lr = lane&15, kg = lane>>4;
  const int clus = blk>>4, r = blk&15;
  const int cbase = clus<<4;
  const int bown = cbase + r;
  const int n0 = r*128;

  uint32_t* flags = (uint32_t*)(ws+OFF_SYNC);
  char* qpg = (char*)(ws+OFF_QP);
  const f16* wstar = (const f16*)(ws+OFF_WSTAR);
  const f16* uk16  = (const f16*)(ws+OFF_UK16);
  const f16* wqswz = (const f16*)(ws+OFF_WQSWZ);
  const f16* keys16= (const f16*)(ws+OFF_KEYS);
  const f16* mem16 = (const f16*)(ws+OFF_MEM16);
  const float* embw= (const float*)(ws+OFF_EMBW);

  __shared__ __align__(16) char  ybuf[33024];
  __shared__ __align__(16) float zl[16*132];
  __shared__ __align__(16) float c_sl[512];
  __shared__ __align__(16) f16   h_sl[512];
  __shared__ __align__(16) float q_l[512];
  __shared__ __align__(16) float v_l[512];
  __shared__ __align__(16) f16   cx16_l[512];
  __shared__ __align__(16) float sc_l[64];
  __shared__ __align__(16) f16   mem_lds[60*512];

  v_l[tid] = v_att[tid];
  { int b = tid>>5, uu = tid&31;
    c_sl[tid] = c0[(size_t)(cbase+b)*512 + r*32 + uu]; }

  {
    const char* msrc = (const char*)(mem16 + (size_t)bown*60*512);
    #pragma unroll
    for (int i=0;i<8;i++){
      int cb2 = i*512 + wave*64;
      if (cb2 < 3840)
        gload16(msrc + ((size_t)cb2 + lane)*16, (char*)mem_lds + (size_t)cb2*16);
    }
  }

  for (int t=0; t<TOUT; t++){
    // A: gather y(t-1) (wide sc1)
    {
      const char* ysrc; int rsh;
      if (t == 0) { ysrc = ws+OFF_H016; rsh = 6; }
      else        { ysrc = ws+OFF_YALL + (size_t)(t-1)*64*2048; rsh = 7; }
      const int npass = (16 << rsh) >> 9;
      u32x4 g[4];
      #pragma unroll
      for (int p=0;p<4;p++){
        if (p < npass){
          int cid = p*512 + tid, row = cid>>rsh, off = cid & ((1<<rsh)-1);
          ld16_sc1(ysrc + ((size_t)(cbase+row) << (rsh+4)) + off*16, g[p]);
        }
      }
      vwait();
      #pragma unroll
      for (int p=0;p<4;p++){
        if (p < npass){
          int cid = p*512 + tid, row = cid>>rsh, off = cid & ((1<<rsh)-1);
          *(u32x4*)(ybuf + row*2064 + off*16) = g[p];
        }
      }
      __syncthreads();
    }

    // B: P1 z[16 b][own 128 cols] via MFMA -> LDS
    {
      const int col = n0 + wave*16 + lr;
      f32x4 acc = (t==0) ? p1_mfma<16>(uk16,  ybuf, col, kg, lr)
                         : p1_mfma<32>(wstar, ybuf, col, kg, lr);
      #pragma unroll
      for (int rr=0;rr<4;rr++)
        zl[(kg*4+rr)*132 + wave*16 + lr] = acc[rr];
    }
    __syncthreads();

    // gates + c/h update
    {
      const int b = tid>>5, uu = tid&31;
      f32x4 zz = *(const f32x4*)(zl + b*132 + uu*4);
      f32x4 e  = *(const f32x4*)(embw + ((size_t)(t*64+cbase+b))*2048 + n0 + uu*4);
      float ig = sigm(zz[0]+e[0]), fg = sigm(zz[1]+e[1]);
      float gg = tanhf(zz[2]+e[2]), og = sigm(zz[3]+e[3]);
      float cn = fg*c_sl[tid] + ig*gg;
      c_sl[tid] = cn;
      h_sl[tid] = (f16)(og * tanhf(cn));
    }
    __syncthreads();

    // C: publish h slices
    char* yt = (char*)(ws+OFF_YALL) + (size_t)t*64*2048;
    if (tid < 64){
      int b = tid>>2, off = tid&3;
      u32x4 v = *(const u32x4*)((const char*)h_sl + b*64 + off*16);
      st16_sc1(yt + (size_t)(cbase+b)*2048 + r*64 + off*16, v);
    }

    // D: q_part = h_slice @ Wq_slice -> LDS stage, publish wide
    {
      float* qs = (float*)ybuf;
      f16x8 a = *(const f16x8*)(h_sl + lr*32 + kg*8);
      #pragma unroll
      for (int j=0;j<4;j++){
        int n = wave*64 + j*16 + lr;
        f16x8 bf = *(const f16x8*)(wqswz + ((size_t)(r*512 + n))*32 + kg*8);
        f32x4 aq = __builtin_amdgcn_mfma_f32_16x16x32_f16(a, bf, (f32x4){0.f,0.f,0.f,0.f}, 0,0,0);
        #pragma unroll
        for (int rr=0;rr<4;rr++)
          qs[(kg*4+rr)*512 + n] = aq[rr];
      }
    }
    __syncthreads();
    {
      #pragma unroll
      for (int p=0;p<4;p++){
        int cid = p*512 + tid;
        u32x4 v = *(const u32x4*)(ybuf + cid*16);
        st16_sc1(qpg + (size_t)blk*32768 + cid*16, v);
      }
    }
    cbar(flags, cbase, r, tid, 2*t+1);

    // F: gather own batch's 16 q-partials, sum
    {
      u32x4 gq[4];
      #pragma unroll
      for (int p=0;p<4;p++){
        int cid = p*512 + tid, s = cid>>7, off = cid&127;
        ld16_sc1(qpg + (size_t)(cbase+s)*32768 + r*2048 + off*16, gq[p]);
      }
      vwait();
      #pragma unroll
      for (int p=0;p<4;p++){
        int cid = p*512 + tid;
        *(u32x4*)(ybuf + cid*16) = gq[p];
      }
      __syncthreads();
      const float* qin = (const float*)ybuf;
      float qsum = 0.f;
      #pragma unroll
      for (int s=0;s<16;s++) qsum += qin[s*512 + tid];
      q_l[tid] = qsum;
    }
    __syncthreads();

    // G: scores -> softmax -> ctx
    for (int i = wave; i < 60; i += 8){
      const f16* krow = keys16 + ((size_t)(bown*60+i))*512;
      float p = 0.f;
      #pragma unroll
      for (int s=0;s<8;s++){
        int u = lane + s*64;
        p += tanh_fast((float)krow[u] + q_l[u]) * v_l[u];
      }
      #pragma unroll
      for (int m=32;m;m>>=1) p += __shfl_xor(p, m, 64);
      if (lane == 0) sc_l[i] = p;
    }
    __syncthreads();
    if (wave == 0){
      float s = (lane < 60) ? sc_l[lane] : -1e30f;
      float mx = s;
      #pragma unroll
      for (int m=32;m;m>>=1) mx = fmaxf(mx, __shfl_xor(mx, m, 64));
      float ev = (lane < 60) ? __expf(s - mx) : 0.f;
      float sum = ev;
      #pragma unroll
      for (int m=32;m;m>>=1) sum += __shfl_xor(sum, m, 64);
      if (lane < 60) sc_l[lane] = ev / sum;
    }
    __syncthreads();
    {
      float cx = 0.f;
      #pragma unroll
      for (int i=0;i<60;i++) cx += sc_l[i] * (float)mem_lds[i*512 + tid];
      cx16_l[tid] = (f16)cx;
    }
    __syncthreads();
    if (tid < 64){
      u32x4 v = *(const u32x4*)((const char*)cx16_l + tid*16);
      st16_sc1(yt + (size_t)bown*2048 + 1024 + tid*16, v);
    }
    cbar(flags, cbase, r, tid, 2*t+2);
  }
}

// ---------------- host ----------------
extern "C" void kernel_launch(void* const* d_in, const int* in_sizes, int n_in,
                              void* d_out, int out_size, void* d_ws, size_t ws_size,
                              hipStream_t stream)
{
  const int*   dec  = (const int*)  d_in[0];
  const float* h0   = (const float*)d_in[1];
  const float* c0   = (const float*)d_in[2];
  const float* mem  = (const float*)d_in[3];
  const float* embt = (const float*)d_in[4];
  const float* Wk   = (const float*)d_in[5];
  const float* Uk   = (const float*)d_in[6];
  const float* bk   = (const float*)d_in[7];
  const float* Wm   = (const float*)d_in[8];
  const float* Wq   = (const float*)d_in[9];
  const float* va   = (const float*)d_in[10];
  const float* Wa   = (const float*)d_in[11];
  const float* Wfc  = (const float*)d_in[12];
  const float* bfc  = (const float*)d_in[13];
  char* ws = (char*)d_ws;

  hipMemsetAsync(ws + OFF_SYNC, 0, 8192, stream);

  // prep (elementwise + swizzles) in one dispatch
  prep_all<<<976, 256, 0, stream>>>(ws, dec, h0, mem, embt, Wa, bk, Wm, Wk, Uk, Wq);

  // keys | embW | Wca fused in one dispatch
  gemm3<<<1008, 256, 0, stream>>>(ws);

  build_wstar<<<256, 256, 0, stream>>>(ws, Uk);

  // recurrence (blocks 0-63) + Wfc conversion hidden in the same dispatch (64-203)
  recur_wfc<<<204, 512, 0, stream>>>(ws, c0, va, Wfc);

  // attn_all = Y @ Wa : [1984,512] f16
  gemm16<128,64,2,2,1><<<dim3(8,16), 256, 0, stream>>>(
      (const f16*)(ws+OFF_YALL), 1024, (const f16*)(ws+OFF_WASWZ), 512,
      ws+OFF_ATT16, nullptr, 1984, 1024, 1984, 512);

  // logits = attn_all @ Wfc + bfc -> d_out [b][t][vocab]  (R7/R11 proven shape)
  gemm16<256,128,4,2,2><<<dim3(266,8), 512, 0, stream>>>(
      (const f16*)(ws+OFF_ATT16), 512, (const f16*)(ws+OFF_WFC), VOCP,
      d_out, bfc, 1984, 512, 1984, VOC);
}

// Round 14
// 764.594 us; speedup vs baseline: 1.0710x; 1.0024x over previous
//
#include <hip/hip_runtime.h>
#include <cstdint>
#include <cstddef>

typedef _Float16 f16;
typedef _Float16 f16x8 __attribute__((ext_vector_type(8)));
typedef float    f32x4 __attribute__((ext_vector_type(4)));
typedef uint32_t u32x4 __attribute__((ext_vector_type(4)));

#define DEV static __device__ __forceinline__

constexpr int TOUT = 31;
constexpr int VOC  = 34004;
constexpr int VOCP = 34048;

// ---------------- ws layout (bytes) ----------------
constexpr size_t OFF_SYNC  = 0;                                         // 8192 (64 flags @128B)
constexpr size_t OFF_MEM16 = 8192;                                      // [3840][512] f16
constexpr size_t OFF_WMSWZ = OFF_MEM16 + (size_t)3840*512*2;            // [16][512][32] f16
constexpr size_t OFF_KEYS  = OFF_WMSWZ + (size_t)16*512*32*2;           // [3840][512] f16
constexpr size_t OFF_EMBA  = OFF_KEYS  + (size_t)3840*512*2;            // [1984][320] f16 (prep-only)
constexpr size_t OFF_WKTOP = OFF_EMBA  + (size_t)1984*320*2;            // [10][2048][32] f16 (prep-only)
constexpr size_t OFF_EMBW  = OFF_WKTOP + (size_t)10*2048*32*2;          // [1984][2048] f32 (perm cols)
constexpr size_t OFF_WA16  = OFF_EMBW  + (size_t)1984*2048*4;           // [1024][512] f16 rowmajor
constexpr size_t OFF_WKATT = OFF_WA16  + (size_t)1024*512*2;            // [16][2048][32] f16 (perm)
constexpr size_t OFF_WCA   = OFF_WKATT + (size_t)16*2048*32*2;          // [1024][2048] f32 (perm cols)
constexpr size_t OFF_WSTAR = OFF_WCA   + (size_t)1024*2048*4;           // [32][2048][32] f16 (perm)
constexpr size_t OFF_UK16  = OFF_WSTAR + (size_t)32*2048*32*2;          // [16][2048][32] f16 (perm)
constexpr size_t OFF_WQSWZ = OFF_UK16  + (size_t)16*2048*32*2;          // [16 r][512 n][32 kk] f16
constexpr size_t OFF_WASWZ = OFF_WQSWZ + (size_t)512*512*2;             // [32][512][32] f16
constexpr size_t OFF_H016  = OFF_WASWZ + (size_t)32*512*32*2;           // [64][512] f16
constexpr size_t OFF_YALL  = OFF_H016  + (size_t)64*512*2;              // [31][64][1024] f16
constexpr size_t OFF_ATT16 = OFF_YALL  + (size_t)31*64*1024*2;          // [1984][512] f16
constexpr size_t OFF_BKP   = OFF_ATT16 + (size_t)1984*512*2;            // [2048] f32 (perm bk)
constexpr size_t OFF_WFC   = OFF_BKP   + 8192;                          // [16][34048][32] f16
// q_part scratch aliases prep-only EMBA/WKTOP: [64 blk][16 b][512] f32 = 2 MB
constexpr size_t OFF_QP    = OFF_EMBA;

// ---------------- helpers ----------------
DEV void gload16(const void* src, void* ldsbase /* wave-uniform */) {
  __builtin_amdgcn_global_load_lds(
      (const __attribute__((address_space(1))) unsigned int*)src,
      (__attribute__((address_space(3))) unsigned int*)ldsbase, 16, 0, 0);
}

DEV float sigm(float x)      { return 1.f / (1.f + expf(-x)); }
DEV float tanh_fast(float x) { float e = __expf(2.f*x); return 1.f - 2.f/(e+1.f); }

DEV uint32_t aload_u32(const uint32_t* p){ return __hip_atomic_load(p, __ATOMIC_RELAXED, __HIP_MEMORY_SCOPE_AGENT); }
DEV void astore_u32(uint32_t* p, uint32_t v){ __hip_atomic_store(p, v, __ATOMIC_RELAXED, __HIP_MEMORY_SCOPE_AGENT); }

// wide agent-scope (sc1) transport
DEV void ld16_sc1(const void* p, u32x4& d){
  asm volatile("global_load_dwordx4 %0, %1, off sc1" : "=v"(d) : "v"(p));
}
DEV void st16_sc1(void* p, u32x4 v){
  asm volatile("global_store_dwordx4 %0, %1, off sc1" :: "v"(p), "v"(v) : "memory");
}
DEV void vwait(){ asm volatile("s_waitcnt vmcnt(0)" ::: "memory"); }

// ---------------- prep_all: elementwise conversions + swizzled B-layouts ----------------
__global__ void prep_all(char* ws, const int* dec, const float* h0, const float* memory,
                         const float* embt, const float* Wa, const float* bk,
                         const float* Wm, const float* Wk, const float* Uk, const float* Wq)
{
  const int blk = blockIdx.x, tid = threadIdx.x;

  if (blk < 464) {
    int tg = blk*256 + tid;
    constexpr int S0=8192, S1=S0+20480, S2=S1+32768, S3=S2+32768, S4=S3+16384, S5=S4+8192;
    if (tg >= S5) return;
    f16 buf[32];
    f16* dst;
    if (tg < S0) {                       // Wm -> [16][512][32]
      int kt=tg>>9, n=tg&511;
      #pragma unroll
      for (int kk=0;kk<32;kk++) buf[kk] = (f16)Wm[(size_t)(kt*32+kk)*512 + n];
      dst = (f16*)(ws+OFF_WMSWZ) + (size_t)tg*32;
    } else if (tg < S1) {                // Wk rows 0..299 (pad->320), perm cols -> [10][2048][32]
      int j=tg-S0; int kt=j>>11, np=j&2047; int col=(np>>2)+(np&3)*512;
      #pragma unroll
      for (int kk=0;kk<32;kk++){ int k=kt*32+kk;
        buf[kk] = (k<300) ? (f16)Wk[(size_t)k*2048+col] : (f16)0.f; }
      dst = (f16*)(ws+OFF_WKTOP) + (size_t)j*32;
    } else if (tg < S2) {                // Wk rows 300..811, perm -> [16][2048][32]
      int j=tg-S1; int kt=j>>11, np=j&2047; int col=(np>>2)+(np&3)*512;
      #pragma unroll
      for (int kk=0;kk<32;kk++) buf[kk] = (f16)Wk[(size_t)(300+kt*32+kk)*2048+col];
      dst = (f16*)(ws+OFF_WKATT) + (size_t)j*32;
    } else if (tg < S3) {                // Uk, perm -> [16][2048][32]
      int j=tg-S2; int kt=j>>11, np=j&2047; int col=(np>>2)+(np&3)*512;
      #pragma unroll
      for (int kk=0;kk<32;kk++) buf[kk] = (f16)Uk[(size_t)(kt*32+kk)*2048+col];
      dst = (f16*)(ws+OFF_UK16) + (size_t)j*32;
    } else if (tg < S4) {                // Wa -> [32][512][32]
      int j=tg-S3; int kt=j>>9, n=j&511;
      #pragma unroll
      for (int kk=0;kk<32;kk++) buf[kk] = (f16)Wa[(size_t)(kt*32+kk)*512 + n];
      dst = (f16*)(ws+OFF_WASWZ) + (size_t)j*32;
    } else {                             // Wq -> [16 r][512 n][32 kk]
      int j=tg-S4; int rr=j>>9, n=j&511;
      #pragma unroll
      for (int kk=0;kk<32;kk++) buf[kk] = (f16)Wq[(size_t)(rr*32+kk)*512 + n];
      dst = (f16*)(ws+OFF_WQSWZ) + (size_t)j*32;
    }
    f16x8* d8 = (f16x8*)dst; f16x8* s8 = (f16x8*)buf;
    d8[0]=s8[0]; d8[1]=s8[1]; d8[2]=s8[2]; d8[3]=s8[3];
    return;
  }

  f16* mem16 = (f16*)(ws+OFF_MEM16);
  f16* embA  = (f16*)(ws+OFF_EMBA);
  f16* wa16  = (f16*)(ws+OFF_WA16);
  f16* h016  = (f16*)(ws+OFF_H016);
  float* bkp = (float*)(ws+OFF_BKP);
  constexpr int E0=1966080, E1=E0+634880, E2=E1+524288, E3=E2+32768, E4=E3+2048;
  for (int i = (blk-464)*256 + tid; i < E4; i += 512*256) {
    if (i < E0) { mem16[i] = (f16)memory[i]; }
    else if (i < E1) { int j=i-E0; int r=j/320, k=j-r*320; int t=r>>6, b=r&63;
      int tok = dec[b*TOUT+t];
      embA[j] = (k<300) ? (f16)embt[(size_t)tok*300+k] : (f16)0.f; }
    else if (i < E2) { int j=i-E1; wa16[j] = (f16)Wa[j]; }
    else if (i < E3) { int j=i-E2; h016[j] = (f16)h0[j]; }
    else { int j=i-E3; bkp[j] = bk[(j>>2) + (j&3)*512]; }
  }
}

// ---------------- gemm3: keys | embW | Wca fused in one dispatch ----------------
__global__ __launch_bounds__(256, 1)
void gemm3(char* ws)
{
  constexpr int BM=128, BN=64, NT=256, AM=4, AN=2, NLA=2, NLB=1;
  __shared__ __align__(16) f16 sA[BM*32];
  __shared__ __align__(16) f16 sB[BN*32];

  const int blk = blockIdx.x, tid = threadIdx.x;
  const int wave = tid>>6, lane = tid&63;
  const int lg = lane>>4, lr = lane&15;

  const f16* A; int lda; const f16* Bs; int Np; void* C; const float* bias = nullptr;
  int bx, by, K, Mreal, mode;
  if (blk < 240) {           // keys = mem16 @ WMSWZ -> f16 [3840,512]
    bx = blk & 7; by = blk >> 3;
    A=(const f16*)(ws+OFF_MEM16); lda=512; Bs=(const f16*)(ws+OFF_WMSWZ); Np=512;
    C=ws+OFF_KEYS; K=512; Mreal=3840; mode=1;
  } else if (blk < 752) {    // embW = embA @ WKTOP + bkp -> f32 [1984,2048]
    int i=blk-240; bx=i&31; by=i>>5;
    A=(const f16*)(ws+OFF_EMBA); lda=320; Bs=(const f16*)(ws+OFF_WKTOP); Np=2048;
    C=ws+OFF_EMBW; bias=(const float*)(ws+OFF_BKP); K=320; Mreal=1984; mode=0;
  } else {                   // Wca = Wa16 @ WKATT -> f32 [1024,2048]
    int i=blk-752; bx=i&31; by=i>>5;
    A=(const f16*)(ws+OFF_WA16); lda=512; Bs=(const f16*)(ws+OFF_WKATT); Np=2048;
    C=ws+OFF_WCA; K=512; Mreal=1024; mode=0;
  }
  const int m0 = by*BM, n0 = bx*BN;
  const int wm = (wave>>1)*64, wn = (wave&1)*32;

  f32x4 acc[AM][AN] = {};
  int aoff[AM], boff[AN];
  #pragma unroll
  for (int i=0;i<AM;i++){ int row = wm+i*16+lr; aoff[i] = row*64 + (((lg + (row>>1))&3)<<4); }
  #pragma unroll
  for (int i=0;i<AN;i++){ int row = wn+i*16+lr; boff[i] = row*64 + (((lg + (row>>1))&3)<<4); }

  const int ksteps = K/32;
  for (int ks=0; ks<ksteps; ks++){
    const int k0 = ks*32;
    __syncthreads();
    #pragma unroll
    for (int i=0;i<NLA;i++){
      int p = i*NT + tid;
      int row = p>>2; int g = ((p&3) - (row>>1)) & 3;
      int gm = m0+row; if (gm > Mreal-1) gm = Mreal-1;
      gload16(A + (size_t)gm*lda + k0 + g*8, (char*)sA + (i*NT + wave*64)*16);
    }
    #pragma unroll
    for (int i=0;i<NLB;i++){
      int p = i*NT + tid;
      int row = p>>2; int g = ((p&3) - (row>>1)) & 3;
      gload16(Bs + ((size_t)(k0>>5)*Np + (n0+row))*32 + g*8, (char*)sB + (i*NT + wave*64)*16);
    }
    __syncthreads();
    f16x8 af[AM], bf[AN];
    #pragma unroll
    for (int i=0;i<AM;i++) af[i] = *(const f16x8*)((const char*)sA + aoff[i]);
    #pragma unroll
    for (int i=0;i<AN;i++) bf[i] = *(const f16x8*)((const char*)sB + boff[i]);
    #pragma unroll
    for (int i=0;i<AM;i++)
      #pragma unroll
      for (int j=0;j<AN;j++)
        acc[i][j] = __builtin_amdgcn_mfma_f32_16x16x32_f16(af[i], bf[j], acc[i][j], 0,0,0);
  }

  #pragma unroll
  for (int i=0;i<AM;i++)
    #pragma unroll
    for (int j=0;j<AN;j++){
      int n = n0 + wn + j*16 + lr;
      float bb = (mode == 0 && bias) ? bias[n] : 0.f;
      #pragma unroll
      for (int r=0;r<4;r++){
        int m = m0 + wm + i*16 + lg*4 + r;
        if (m >= Mreal) continue;
        float v = acc[i][j][r] + bb;
        if (mode == 0) ((float*)C)[(size_t)m*Np + n] = v;
        else           ((f16*)C)[(size_t)m*Np + n] = (f16)v;
      }
    }
}

// ---------------- build W* = Wca + [Uk;0] -> [32][2048][32] (perm) ----------------
__global__ void build_wstar(char* ws, const float* Uk)
{
  int tg = blockIdx.x*256 + threadIdx.x;
  int kt = tg>>11, np = tg&2047;
  int col = (np>>2)+(np&3)*512;
  const float* wca = (const float*)(ws+OFF_WCA);
  f16 buf[32];
  #pragma unroll
  for (int kk=0;kk<32;kk++){
    int k = kt*32+kk;
    float v = wca[(size_t)k*2048 + np];
    if (k < 512) v += Uk[(size_t)k*2048 + col];
    buf[kk] = (f16)v;
  }
  f16* dst = (f16*)(ws+OFF_WSTAR) + (size_t)tg*32;
  f16x8* d8 = (f16x8*)dst; f16x8* s8 = (f16x8*)buf;
  d8[0]=s8[0]; d8[1]=s8[1]; d8[2]=s8[2]; d8[3]=s8[3];
}

// ---------------- generic fp16 MFMA GEMM (att) ----------------
template<int BM, int BN, int WR, int WC, int MODE>
__global__ __launch_bounds__(WR*WC*64, 1)
void gemm16(const f16* __restrict__ A, int lda,
            const f16* __restrict__ Bs, int Np,
            void* __restrict__ C, const float* __restrict__ bias,
            int M, int K, int Mreal, int Nreal)
{
  constexpr int NT  = WR*WC*64;
  constexpr int WTM = BM/WR, WTN = BN/WC, AM = WTM/16, AN = WTN/16;
  constexpr int NLA = BM*64/(NT*16), NLB = BN*64/(NT*16);
  __shared__ __align__(16) f16 sA[BM*32];
  __shared__ __align__(16) f16 sB[BN*32];
  const int tid = threadIdx.x, wave = tid>>6, lane = tid&63;
  const int lg = lane>>4, lr = lane&15;
  const int m0 = blockIdx.y*BM, n0 = blockIdx.x*BN;
  const int wm = (wave/WC)*WTM, wn = (wave%WC)*WTN;

  f32x4 acc[AM][AN] = {};

  int aoff[AM], boff[AN];
  #pragma unroll
  for (int i=0;i<AM;i++){ int row = wm+i*16+lr; aoff[i] = row*64 + (((lg + (row>>1))&3)<<4); }
  #pragma unroll
  for (int i=0;i<AN;i++){ int row = wn+i*16+lr; boff[i] = row*64 + (((lg + (row>>1))&3)<<4); }

  const int ksteps = K/32;
  for (int ks=0; ks<ksteps; ks++){
    const int k0 = ks*32;
    __syncthreads();
    #pragma unroll
    for (int i=0;i<NLA;i++){
      int p = i*NT + tid;
      int row = p>>2; int g = ((p&3) - (row>>1)) & 3;
      int gm = m0+row; if (gm > Mreal-1) gm = Mreal-1;
      gload16(A + (size_t)gm*lda + k0 + g*8, (char*)sA + (i*NT + wave*64)*16);
    }
    #pragma unroll
    for (int i=0;i<NLB;i++){
      int p = i*NT + tid;
      int row = p>>2; int g = ((p&3) - (row>>1)) & 3;
      gload16(Bs + ((size_t)(k0>>5)*Np + (n0+row))*32 + g*8, (char*)sB + (i*NT + wave*64)*16);
    }
    __syncthreads();
    f16x8 af[AM], bf[AN];
    #pragma unroll
    for (int i=0;i<AM;i++) af[i] = *(const f16x8*)((const char*)sA + aoff[i]);
    #pragma unroll
    for (int i=0;i<AN;i++) bf[i] = *(const f16x8*)((const char*)sB + boff[i]);
    #pragma unroll
    for (int i=0;i<AM;i++)
      #pragma unroll
      for (int j=0;j<AN;j++)
        acc[i][j] = __builtin_amdgcn_mfma_f32_16x16x32_f16(af[i], bf[j], acc[i][j], 0,0,0);
  }

  #pragma unroll
  for (int i=0;i<AM;i++)
    #pragma unroll
    for (int j=0;j<AN;j++){
      int n = n0 + wn + j*16 + lr;
      if (MODE == 2 && n >= Nreal) continue;
      float bb = 0.f;
      if (MODE != 1 && bias) bb = bias[n];
      #pragma unroll
      for (int r=0;r<4;r++){
        int m = m0 + wm + i*16 + lg*4 + r;
        if (m >= Mreal) continue;
        float v = acc[i][j][r] + bb;
        if (MODE == 0)      ((float*)C)[(size_t)m*Np + n] = v;
        else if (MODE == 1) ((f16*)C)[(size_t)m*Np + n] = (f16)v;
        else { int t = m>>6, b = m&63; ((float*)C)[((size_t)(b*TOUT+t))*VOC + n] = v; }
      }
    }
}

// ---------------- logits GEMM: BM=256,BN=128, XCD-aware block swizzle ----------------
// flat = xcd*266 + k  (xcd = blk%8, k = blk/8)  ->  (bx,by) = (flat/8, flat%8).
// Bijective over 2128 blocks; each XCD covers ~33 consecutive bx slices x all 8 by
// -> per-XCD Wfc working set ~4.4 MB (L2-resident) instead of touching all 35 MB.
__global__ __launch_bounds__(512, 1)
void gemm_logits(const f16* __restrict__ A,
                 const f16* __restrict__ Bs,
                 float* __restrict__ out, const float* __restrict__ bias)
{
  constexpr int BM=256, BN=128, NT=512, AM=4, AN=4, NLA=2, NLB=1;
  __shared__ __align__(16) f16 sA[BM*32];
  __shared__ __align__(16) f16 sB[BN*32];
  const int tid = threadIdx.x, wave = tid>>6, lane = tid&63;
  const int lg = lane>>4, lr = lane&15;

  const int flat = (blockIdx.x & 7)*266 + (blockIdx.x >> 3);
  const int bx = flat >> 3, by = flat & 7;
  const int m0 = by*BM, n0 = bx*BN;
  const int wm = (wave/2)*64, wn = (wave&1)*64;   // WR=4, WC=2

  f32x4 acc[AM][AN] = {};

  int aoff[AM], boff[AN];
  #pragma unroll
  for (int i=0;i<AM;i++){ int row = wm+i*16+lr; aoff[i] = row*64 + (((lg + (row>>1))&3)<<4); }
  #pragma unroll
  for (int i=0;i<AN;i++){ int row = wn+i*16+lr; boff[i] = row*64 + (((lg + (row>>1))&3)<<4); }

  for (int ks=0; ks<16; ks++){
    const int k0 = ks*32;
    __syncthreads();
    #pragma unroll
    for (int i=0;i<NLA;i++){
      int p = i*NT + tid;
      int row = p>>2; int g = ((p&3) - (row>>1)) & 3;
      int gm = m0+row; if (gm > 1983) gm = 1983;
      gload16(A + (size_t)gm*512 + k0 + g*8, (char*)sA + (i*NT + wave*64)*16);
    }
    {
      int p = tid;
      int row = p>>2; int g = ((p&3) - (row>>1)) & 3;
      gload16(Bs + ((size_t)ks*VOCP + (n0+row))*32 + g*8, (char*)sB + (wave*64)*16);
    }
    __syncthreads();
    f16x8 af[AM], bf[AN];
    #pragma unroll
    for (int i=0;i<AM;i++) af[i] = *(const f16x8*)((const char*)sA + aoff[i]);
    #pragma unroll
    for (int i=0;i<AN;i++) bf[i] = *(const f16x8*)((const char*)sB + boff[i]);
    #pragma unroll
    for (int i=0;i<AM;i++)
      #pragma unroll
      for (int j=0;j<AN;j++)
        acc[i][j] = __builtin_amdgcn_mfma_f32_16x16x32_f16(af[i], bf[j], acc[i][j], 0,0,0);
  }

  #pragma unroll
  for (int i=0;i<AM;i++)
    #pragma unroll
    for (int j=0;j<AN;j++){
      int n = n0 + wn + j*16 + lr;
      if (n >= VOC) continue;
      float bb = bias[n];
      #pragma unroll
      for (int r=0;r<4;r++){
        int m = m0 + wm + i*16 + lg*4 + r;
        if (m >= 1984) continue;
        int t = m>>6, b = m&63;
        out[((size_t)(b*TOUT+t))*VOC + n] = acc[i][j][r] + bb;
      }
    }
}

// ---------------- cluster barrier: sc1 flag array (proven) ----------------
DEV void cbar(uint32_t* flags, int cbase, int r, int tid, uint32_t target)
{
  vwait();
  __syncthreads();
  if (tid == 0)
    astore_u32(flags + (size_t)(cbase + r)*32, target);
  if (tid < 16) {
    while (aload_u32(flags + (size_t)(cbase + tid)*32) < target)
      __builtin_amdgcn_s_sleep(1);
  }
  __syncthreads();
}

// ---------------- P1 inner: one 16x16 tile over K, 8-deep B prefetch ----------------
template<int KS>
DEV f32x4 p1_mfma(const f16* __restrict__ Bs, const char* ylb, int col, int kg, int lr)
{
  f16x8 B[8];
  #pragma unroll
  for (int i=0;i<8;i++)
    B[i] = *(const f16x8*)(Bs + (((size_t)i*2048 + col)<<5) + kg*8);
  f32x4 acc = {};
  #pragma unroll
  for (int ks=0; ks<KS; ks+=8) {
    #pragma unroll
    for (int i=0;i<8;i++) {
      f16x8 a = *(const f16x8*)(ylb + lr*2064 + (ks+i)*64 + kg*16);
      acc = __builtin_amdgcn_mfma_f32_16x16x32_f16(a, B[i], acc, 0,0,0);
      int nk = ks+8+i;
      if (nk < KS)
        B[i] = *(const f16x8*)(Bs + (((size_t)nk*2048 + col)<<5) + kg*8);
    }
  }
  return acc;
}

// ---------------- recur (blocks 0-63) + independent Wfc converters (64-203) ----------------
__global__ __launch_bounds__(512, 1)
void recur_wfc(char* ws, const float* __restrict__ c0, const float* __restrict__ v_att,
               const float* __restrict__ Wfc)
{
  const int blk = blockIdx.x, tid = threadIdx.x;

  if (blk >= 64) {
    const int cb = blk - 64;                      // 0..139
    const int n = cb*256 + (tid & 255);
    const int kt0 = (tid >> 8) * 8;
    if (n < VOCP) {
      f16* wdst = (f16*)(ws+OFF_WFC);
      for (int kt = kt0; kt < kt0+8; kt++) {
        f16 buf[32];
        #pragma unroll
        for (int kk=0;kk<32;kk++)
          buf[kk] = (n < VOC) ? (f16)Wfc[(size_t)(kt*32+kk)*VOC + n] : (f16)0.f;
        f16x8* d8 = (f16x8*)((f16*)wdst + ((size_t)kt*VOCP + n)*32);
        f16x8* s8 = (f16x8*)buf;
        d8[0]=s8[0]; d8[1]=s8[1]; d8[2]=s8[2]; d8[3]=s8[3];
      }
    }
    return;
  }

  // -------------------- recur role (R7, proven) --------------------
  const int wave = tid>>6, lane = tid&63;
  const int lr = lane&15, kg = lane>>4;
  const int clus = blk>>4, r = blk&15;
  const int cbase = clus<<4;
  const int bown = cbase + r;
  const int n0 = r*128;

  uint32_t* flags = (uint32_t*)(ws+OFF_SYNC);
  char* qpg = (char*)(ws+OFF_QP);
  const f16* wstar = (const f16*)(ws+OFF_WSTAR);
  const f16* uk16  = (const f16*)(ws+OFF_UK16);
  const f16* wqswz = (const f16*)(ws+OFF_WQSWZ);
  const f16* keys16= (const f16*)(ws+OFF_KEYS);
  const f16* mem16 = (const f16*)(ws+OFF_MEM16);
  const float* embw= (const float*)(ws+OFF_EMBW);

  __shared__ __align__(16) char  ybuf[33024];
  __shared__ __align__(16) float zl[16*132];
  __shared__ __align__(16) float c_sl[512];
  __shared__ __align__(16) f16   h_sl[512];
  __shared__ __align__(16) float q_l[512];
  __shared__ __align__(16) float v_l[512];
  __shared__ __align__(16) f16   cx16_l[512];
  __shared__ __align__(16) float sc_l[64];
  __shared__ __align__(16) f16   mem_lds[60*512];

  v_l[tid] = v_att[tid];
  { int b = tid>>5, uu = tid&31;
    c_sl[tid] = c0[(size_t)(cbase+b)*512 + r*32 + uu]; }

  {
    const char* msrc = (const char*)(mem16 + (size_t)bown*60*512);
    #pragma unroll
    for (int i=0;i<8;i++){
      int cb2 = i*512 + wave*64;
      if (cb2 < 3840)
        gload16(msrc + ((size_t)cb2 + lane)*16, (char*)mem_lds + (size_t)cb2*16);
    }
  }

  for (int t=0; t<TOUT; t++){
    // A: gather y(t-1) (wide sc1)
    {
      const char* ysrc; int rsh;
      if (t == 0) { ysrc = ws+OFF_H016; rsh = 6; }
      else        { ysrc = ws+OFF_YALL + (size_t)(t-1)*64*2048; rsh = 7; }
      const int npass = (16 << rsh) >> 9;
      u32x4 g[4];
      #pragma unroll
      for (int p=0;p<4;p++){
        if (p < npass){
          int cid = p*512 + tid, row = cid>>rsh, off = cid & ((1<<rsh)-1);
          ld16_sc1(ysrc + ((size_t)(cbase+row) << (rsh+4)) + off*16, g[p]);
        }
      }
      vwait();
      #pragma unroll
      for (int p=0;p<4;p++){
        if (p < npass){
          int cid = p*512 + tid, row = cid>>rsh, off = cid & ((1<<rsh)-1);
          *(u32x4*)(ybuf + row*2064 + off*16) = g[p];
        }
      }
      __syncthreads();
    }

    // B: P1 z[16 b][own 128 cols] via MFMA -> LDS
    {
      const int col = n0 + wave*16 + lr;
      f32x4 acc = (t==0) ? p1_mfma<16>(uk16,  ybuf, col, kg, lr)
                         : p1_mfma<32>(wstar, ybuf, col, kg, lr);
      #pragma unroll
      for (int rr=0;rr<4;rr++)
        zl[(kg*4+rr)*132 + wave*16 + lr] = acc[rr];
    }
    __syncthreads();

    // gates + c/h update
    {
      const int b = tid>>5, uu = tid&31;
      f32x4 zz = *(const f32x4*)(zl + b*132 + uu*4);
      f32x4 e  = *(const f32x4*)(embw + ((size_t)(t*64+cbase+b))*2048 + n0 + uu*4);
      float ig = sigm(zz[0]+e[0]), fg = sigm(zz[1]+e[1]);
      float gg = tanhf(zz[2]+e[2]), og = sigm(zz[3]+e[3]);
      float cn = fg*c_sl[tid] + ig*gg;
      c_sl[tid] = cn;
      h_sl[tid] = (f16)(og * tanhf(cn));
    }
    __syncthreads();

    // C: publish h slices
    char* yt = (char*)(ws+OFF_YALL) + (size_t)t*64*2048;
    if (tid < 64){
      int b = tid>>2, off = tid&3;
      u32x4 v = *(const u32x4*)((const char*)h_sl + b*64 + off*16);
      st16_sc1(yt + (size_t)(cbase+b)*2048 + r*64 + off*16, v);
    }

    // D: q_part = h_slice @ Wq_slice -> LDS stage, publish wide
    {
      float* qs = (float*)ybuf;
      f16x8 a = *(const f16x8*)(h_sl + lr*32 + kg*8);
      #pragma unroll
      for (int j=0;j<4;j++){
        int n = wave*64 + j*16 + lr;
        f16x8 bf = *(const f16x8*)(wqswz + ((size_t)(r*512 + n))*32 + kg*8);
        f32x4 aq = __builtin_amdgcn_mfma_f32_16x16x32_f16(a, bf, (f32x4){0.f,0.f,0.f,0.f}, 0,0,0);
        #pragma unroll
        for (int rr=0;rr<4;rr++)
          qs[(kg*4+rr)*512 + n] = aq[rr];
      }
    }
    __syncthreads();
    {
      #pragma unroll
      for (int p=0;p<4;p++){
        int cid = p*512 + tid;
        u32x4 v = *(const u32x4*)(ybuf + cid*16);
        st16_sc1(qpg + (size_t)blk*32768 + cid*16, v);
      }
    }
    cbar(flags, cbase, r, tid, 2*t+1);

    // F: gather own batch's 16 q-partials, sum
    {
      u32x4 gq[4];
      #pragma unroll
      for (int p=0;p<4;p++){
        int cid = p*512 + tid, s = cid>>7, off = cid&127;
        ld16_sc1(qpg + (size_t)(cbase+s)*32768 + r*2048 + off*16, gq[p]);
      }
      vwait();
      #pragma unroll
      for (int p=0;p<4;p++){
        int cid = p*512 + tid;
        *(u32x4*)(ybuf + cid*16) = gq[p];
      }
      __syncthreads();
      const float* qin = (const float*)ybuf;
      float qsum = 0.f;
      #pragma unroll
      for (int s=0;s<16;s++) qsum += qin[s*512 + tid];
      q_l[tid] = qsum;
    }
    __syncthreads();

    // G: scores -> softmax -> ctx
    for (int i = wave; i < 60; i += 8){
      const f16* krow = keys16 + ((size_t)(bown*60+i))*512;
      float p = 0.f;
      #pragma unroll
      for (int s=0;s<8;s++){
        int u = lane + s*64;
        p += tanh_fast((float)krow[u] + q_l[u]) * v_l[u];
      }
      #pragma unroll
      for (int m=32;m;m>>=1) p += __shfl_xor(p, m, 64);
      if (lane == 0) sc_l[i] = p;
    }
    __syncthreads();
    if (wave == 0){
      float s = (lane < 60) ? sc_l[lane] : -1e30f;
      float mx = s;
      #pragma unroll
      for (int m=32;m;m>>=1) mx = fmaxf(mx, __shfl_xor(mx, m, 64));
      float ev = (lane < 60) ? __expf(s - mx) : 0.f;
      float sum = ev;
      #pragma unroll
      for (int m=32;m;m>>=1) sum += __shfl_xor(sum, m, 64);
      if (lane < 60) sc_l[lane] = ev / sum;
    }
    __syncthreads();
    {
      float cx = 0.f;
      #pragma unroll
      for (int i=0;i<60;i++) cx += sc_l[i] * (float)mem_lds[i*512 + tid];
      cx16_l[tid] = (f16)cx;
    }
    __syncthreads();
    if (tid < 64){
      u32x4 v = *(const u32x4*)((const char*)cx16_l + tid*16);
      st16_sc1(yt + (size_t)bown*2048 + 1024 + tid*16, v);
    }
    cbar(flags, cbase, r, tid, 2*t+2);
  }
}

// ---------------- host ----------------
extern "C" void kernel_launch(void* const* d_in, const int* in_sizes, int n_in,
                              void* d_out, int out_size, void* d_ws, size_t ws_size,
                              hipStream_t stream)
{
  const int*   dec  = (const int*)  d_in[0];
  const float* h0   = (const float*)d_in[1];
  const float* c0   = (const float*)d_in[2];
  const float* mem  = (const float*)d_in[3];
  const float* embt = (const float*)d_in[4];
  const float* Wk   = (const float*)d_in[5];
  const float* Uk   = (const float*)d_in[6];
  const float* bk   = (const float*)d_in[7];
  const float* Wm   = (const float*)d_in[8];
  const float* Wq   = (const float*)d_in[9];
  const float* va   = (const float*)d_in[10];
  const float* Wa   = (const float*)d_in[11];
  const float* Wfc  = (const float*)d_in[12];
  const float* bfc  = (const float*)d_in[13];
  char* ws = (char*)d_ws;

  hipMemsetAsync(ws + OFF_SYNC, 0, 8192, stream);

  prep_all<<<976, 256, 0, stream>>>(ws, dec, h0, mem, embt, Wa, bk, Wm, Wk, Uk, Wq);
  gemm3<<<1008, 256, 0, stream>>>(ws);
  build_wstar<<<256, 256, 0, stream>>>(ws, Uk);

  recur_wfc<<<204, 512, 0, stream>>>(ws, c0, va, Wfc);

  // attn_all = Y @ Wa : [1984,512] f16
  gemm16<128,64,2,2,1><<<dim3(8,16), 256, 0, stream>>>(
      (const f16*)(ws+OFF_YALL), 1024, (const f16*)(ws+OFF_WASWZ), 512,
      ws+OFF_ATT16, nullptr, 1984, 1024, 1984, 512);

  // logits = attn_all @ Wfc + bfc (XCD-aware swizzle: per-XCD L2-resident Wfc slices)
  gemm_logits<<<2128, 512, 0, stream>>>(
      (const f16*)(ws+OFF_ATT16), (const f16*)(ws+OFF_WFC), (float*)d_out, bfc);
}